// Round 12
// baseline (319.828 us; speedup 1.0000x reference)
//
// ============================================================================
// Round 12: two-level partition (coarse 512-node buckets -> in-LDS full sort).
//
// Measured R11: 311 us. partition_all 76 us, WRITE 108 MB (predicted 28 --
// MODEL WRONG): amplification is temporal dispersion, not run length. Writes
// to a bucket spread over block lifetime; write set = all P2 (24 MB) vs 4 MB
// per-XCD L2 -> lines evicted ~12B-dirty. Fix = temporal clustering.
// spmm 76 us (FETCH 148 MB, VALU 30%) still pays per-block LDS sort.
//
// Changes:
//  - count_coarse + scan_off (exact offsets, no CAP) + partition_coarse into
//    NC=98 coarse buckets (payload src | (d&511)<<16). Active lines/block =
//    98 (~200 KB/XCD) -> full sectors. Predict WRITE ~21 MB.
//  - sort_fine: block per (coarse,graph): LDS counting sort of ~16K edges by
//    dst, streams out dst-sorted u16 src list S (seq writes, amp 1.0) +
//    exact row_start[N+1]. 
//  - spmm: no sort; load rs[65], stage contiguous S range to LDS, gather.
//  - hist/gemm unchanged (both < top-5 cutoff).
//
// Predicted: coarse ~20 us (WRITE <=25 MB), sort_fine ~30, spmm -> 55-62,
// total 311 -> 255-280. If coarse WRITE still high -> model v2 wrong too.
// ============================================================================
#include <hip/hip_runtime.h>

#define KDIM 128
#define NCOLS 64
// src-degree histogram (u16-packed, 2 ranges)
#define NCHUNK 64
#define NRANGE 2
#define RBINS 25088
#define RWORDS (RBINS / 2)
#define CWORDS (NRANGE * RWORDS)
// coarse buckets
#define COARSE 512
#define NC 98                      // ceil(50000/512)
#define SFCAP 17408                // LDS sort capacity (mean 16384, +8 sigma)
// fine buckets (spmm granularity)
#define BUCKET 64
#define NBUCK 782
#define FCAP 2816                  // mean 2048, +17 sigma
// partition blocks per graph
#define NPB 85

struct GArgs {
  const int*   src[3];
  const int*   dst[3];
  const float* W[3];
  const float* b[3];
  int          E[3];
};

__device__ __forceinline__ unsigned short f2bf(float f) {
  unsigned u = __float_as_uint(f);
  u += 0x7FFFu + ((u >> 16) & 1u);   // RNE
  return (unsigned short)(u >> 16);
}
__device__ __forceinline__ float bflo(unsigned u) { return __uint_as_float(u << 16); }
__device__ __forceinline__ float bfhi(unsigned u) { return __uint_as_float(u & 0xFFFF0000u); }

// ---------------- coarse count --------------------------------------------
__global__ __launch_bounds__(256) void count_coarse_kernel(
    GArgs A, int* __restrict__ tot) {
  __shared__ int hcnt[NC];
  const int g = blockIdx.y;
  const int E = A.E[g];
  const int per_block = (((E + NPB - 1) / NPB) + 3) & ~3;
  const int* __restrict__ dst = A.dst[g];
  const int t = threadIdx.x;
  if (t < NC) hcnt[t] = 0;
  __syncthreads();
  const int e0 = blockIdx.x * per_block;
  const int e1 = min(e0 + per_block, E);
  const int n = max(e1 - e0, 0);
  const int nv = n >> 2;
  const int4* d4 = (const int4*)&dst[e0];
  for (int v = t; v < nv; v += 256) {
    int4 d = d4[v];
    atomicAdd(&hcnt[(unsigned)d.x >> 9], 1);
    atomicAdd(&hcnt[(unsigned)d.y >> 9], 1);
    atomicAdd(&hcnt[(unsigned)d.z >> 9], 1);
    atomicAdd(&hcnt[(unsigned)d.w >> 9], 1);
  }
  for (int e = e0 + (nv << 2) + t; e < e1; e += 256)
    atomicAdd(&hcnt[(unsigned)dst[e] >> 9], 1);
  __syncthreads();
  if (t < NC && hcnt[t]) atomicAdd(&tot[g * NC + t], hcnt[t]);
}

// ---------------- exact scan: off[g][0..NC], cursor init --------------------
__global__ __launch_bounds__(128) void scan_off_kernel(
    const int* __restrict__ tot, int* __restrict__ off, int* __restrict__ cursor) {
  __shared__ int sd[128];
  const int t = threadIdx.x;
  for (int g = 0; g < 3; ++g) {
    int v = (t < NC) ? tot[g * NC + t] : 0;
    sd[t] = v;
    __syncthreads();
    for (int o = 1; o < 128; o <<= 1) {
      int add = (t >= o) ? sd[t - o] : 0;
      __syncthreads();
      sd[t] += add;
      __syncthreads();
    }
    int excl = sd[t] - v;
    if (t < NC) { off[g * (NC + 1) + t] = excl; cursor[g * NC + t] = excl; }
    if (t == 0) off[g * (NC + 1) + NC] = sd[127];
    __syncthreads();
  }
}

// ---------------- coarse partition: P2c[pos] = src | (d&511)<<16 ------------
__global__ __launch_bounds__(256) void partition_coarse_kernel(
    GArgs A, int* __restrict__ cursor, unsigned* __restrict__ P2c, int Emax) {
  __shared__ int lcnt[NC];
  __shared__ int lcur[NC];
  const int g = blockIdx.y;
  const int E = A.E[g];
  const int per_block = (((E + NPB - 1) / NPB) + 3) & ~3;
  const int* __restrict__ src = A.src[g];
  const int* __restrict__ dst = A.dst[g];
  unsigned* __restrict__ P2g = P2c + (size_t)g * Emax;
  const int t = threadIdx.x;
  if (t < NC) lcnt[t] = 0;
  __syncthreads();
  const int e0 = blockIdx.x * per_block;
  const int e1 = min(e0 + per_block, E);
  const int n = max(e1 - e0, 0);
  const int nv = n >> 2;
  const int4* d4 = (const int4*)&dst[e0];
  const int4* s4 = (const int4*)&src[e0];
  for (int v = t; v < nv; v += 256) {
    int4 d = d4[v];
    atomicAdd(&lcnt[(unsigned)d.x >> 9], 1);
    atomicAdd(&lcnt[(unsigned)d.y >> 9], 1);
    atomicAdd(&lcnt[(unsigned)d.z >> 9], 1);
    atomicAdd(&lcnt[(unsigned)d.w >> 9], 1);
  }
  for (int e = e0 + (nv << 2) + t; e < e1; e += 256)
    atomicAdd(&lcnt[(unsigned)dst[e] >> 9], 1);
  __syncthreads();
  if (t < NC) {
    int c = lcnt[t];
    lcur[t] = c ? atomicAdd(&cursor[g * NC + t], c) : 0;
  }
  __syncthreads();
  for (int v = t; v < nv; v += 256) {
    int4 d = d4[v];
    int4 s = s4[v];
    unsigned bk; int pos;
    bk = (unsigned)d.x >> 9; pos = atomicAdd(&lcur[bk], 1);
    P2g[pos] = (unsigned)s.x | (((unsigned)d.x & 511u) << 16);
    bk = (unsigned)d.y >> 9; pos = atomicAdd(&lcur[bk], 1);
    P2g[pos] = (unsigned)s.y | (((unsigned)d.y & 511u) << 16);
    bk = (unsigned)d.z >> 9; pos = atomicAdd(&lcur[bk], 1);
    P2g[pos] = (unsigned)s.z | (((unsigned)d.z & 511u) << 16);
    bk = (unsigned)d.w >> 9; pos = atomicAdd(&lcur[bk], 1);
    P2g[pos] = (unsigned)s.w | (((unsigned)d.w & 511u) << 16);
  }
  for (int e = e0 + (nv << 2) + t; e < e1; e += 256) {
    unsigned d = (unsigned)dst[e];
    unsigned bk = d >> 9;
    int pos = atomicAdd(&lcur[bk], 1);
    P2g[pos] = (unsigned)src[e] | ((d & 511u) << 16);
  }
}

// ---------------- fine sort: coarse bucket -> dst-sorted u16 srcs + rs ------
__global__ __launch_bounds__(512) void sort_fine_kernel(
    const unsigned* __restrict__ P2c, const int* __restrict__ off,
    unsigned short* __restrict__ S, int* __restrict__ row_start,
    int N, int Emax) {
  __shared__ int cnt[COARSE];
  __shared__ int sd[COARSE];
  __shared__ int cur[COARSE];
  __shared__ unsigned short outl[SFCAP];
  const int c = blockIdx.x;
  const int g = blockIdx.y;
  const unsigned* __restrict__ P2g = P2c + (size_t)g * Emax;
  const int base_e = off[g * (NC + 1) + c];
  const int nloc = off[g * (NC + 1) + c + 1] - base_e;
  const int t = threadIdx.x;

  cnt[t] = 0;
  __syncthreads();
  for (int i = t; i < nloc; i += 512)
    atomicAdd(&cnt[(P2g[base_e + i] >> 16) & 511u], 1);
  __syncthreads();
  int v = cnt[t];
  sd[t] = v;
  __syncthreads();
  for (int o = 1; o < 512; o <<= 1) {
    int add = (t >= o) ? sd[t - o] : 0;
    __syncthreads();
    sd[t] += add;
    __syncthreads();
  }
  int excl = sd[t] - v;
  cur[t] = excl;
  int node = c * COARSE + t;
  if (node <= N) row_start[g * (N + 1) + node] = base_e + excl;
  __syncthreads();
  for (int i = t; i < nloc; i += 512) {
    unsigned p = P2g[base_e + i];
    int pos = atomicAdd(&cur[(p >> 16) & 511u], 1);
    if (pos < SFCAP) outl[pos] = (unsigned short)(p & 0xFFFFu);
  }
  __syncthreads();
  unsigned short* __restrict__ Sg = S + (size_t)g * Emax;
  for (int i = t; i < nloc; i += 512) Sg[base_e + i] = outl[i];
}

// ---------------- src histogram partials, u16-packed (unchanged) ------------
__global__ __launch_bounds__(256) void hist_all_kernel(
    GArgs A, unsigned* __restrict__ P) {
  __shared__ unsigned hist[RWORDS];
  const int g = blockIdx.z;
  const int E = A.E[g];
  const int per_chunk = (((E + NCHUNK - 1) / NCHUNK) + 3) & ~3;
  const int* __restrict__ keys = A.src[g];
  unsigned* __restrict__ Pg = P + (size_t)g * NCHUNK * CWORDS;

  const int chunk = blockIdx.x;
  const int base  = blockIdx.y * RBINS;
  const int t = threadIdx.x;
  for (int i = t; i < RWORDS; i += 256) hist[i] = 0;
  __syncthreads();
  const int e0 = chunk * per_chunk;
  const int e1 = min(e0 + per_chunk, E);
  const int n = max(e1 - e0, 0);
  const int nv = n >> 2;
  const int4* k4p = (const int4*)&keys[e0];
  for (int v = t; v < nv; v += 256) {
    int4 k4 = k4p[v];
    unsigned k0 = (unsigned)(k4.x - base);
    unsigned k1 = (unsigned)(k4.y - base);
    unsigned k2 = (unsigned)(k4.z - base);
    unsigned k3 = (unsigned)(k4.w - base);
    if (k0 < (unsigned)RBINS) atomicAdd(&hist[k0 >> 1], 1u << ((k0 & 1u) * 16));
    if (k1 < (unsigned)RBINS) atomicAdd(&hist[k1 >> 1], 1u << ((k1 & 1u) * 16));
    if (k2 < (unsigned)RBINS) atomicAdd(&hist[k2 >> 1], 1u << ((k2 & 1u) * 16));
    if (k3 < (unsigned)RBINS) atomicAdd(&hist[k3 >> 1], 1u << ((k3 & 1u) * 16));
  }
  for (int e = e0 + (nv << 2) + t; e < e1; e += 256) {
    unsigned k = (unsigned)(keys[e] - base);
    if (k < (unsigned)RBINS) atomicAdd(&hist[k >> 1], 1u << ((k & 1u) * 16));
  }
  __syncthreads();
  unsigned* dstp = Pg + (size_t)chunk * CWORDS + blockIdx.y * RWORDS;
  for (int i = t; i < RWORDS; i += 256) dstp[i] = hist[i];
}

// ---------------- x(bf16) = (h @ W_g) * rsqrt(deg) (unchanged R11) ----------
__device__ __forceinline__ void fma4(float4& a, float s, const float4& b) {
  a.x = fmaf(s, b.x, a.x);
  a.y = fmaf(s, b.y, a.y);
  a.z = fmaf(s, b.z, a.z);
  a.w = fmaf(s, b.w, a.w);
}

__global__ __launch_bounds__(256) void gemm_all_kernel(
    GArgs A, const float* __restrict__ h, const unsigned* __restrict__ P,
    unsigned short* __restrict__ x, int N) {
  __shared__ float Ws[KDIM * NCOLS];
  __shared__ int ldeg[128];

  const int g = blockIdx.y;
  const float* __restrict__ W = A.W[g];
  const unsigned* __restrict__ Pg = P + (size_t)g * NCHUNK * CWORDS;
  unsigned short* __restrict__ xg = x + (size_t)g * N * NCOLS;

  const int t = threadIdx.x;
  const int tx = t & 15;
  const int ty = t >> 4;
  const int row0 = blockIdx.x * 128;

  #pragma unroll
  for (int i = 0; i < 8; ++i) {
    int lin = i * 1024 + t * 4;
    *(float4*)&Ws[lin] = *(const float4*)&W[lin];
  }
  {
    int lrow = t >> 1;
    int part = t & 1;
    int row = min(row0 + lrow, N - 1);
    int word = row >> 1;
    int shift = (row & 1) * 16;
    int s = 0;
    #pragma unroll
    for (int c = 0; c < 32; ++c)
      s += (int)((Pg[(size_t)(part * 32 + c) * CWORDS + word] >> shift) & 0xFFFFu);
    ldeg[lrow] = 0;
    __syncthreads();
    atomicAdd(&ldeg[lrow], s);
  }
  __syncthreads();

  int r0 = row0 + 8 * ty;
  const float* hp[8];
  #pragma unroll
  for (int r = 0; r < 8; ++r) hp[r] = &h[(size_t)min(r0 + r, N - 1) * KDIM];

  float4 acc[8];
  #pragma unroll
  for (int r = 0; r < 8; ++r) acc[r] = make_float4(0.f, 0.f, 0.f, 0.f);

  #pragma unroll 2
  for (int k = 0; k < KDIM; k += 4) {
    float4 w0 = *(float4*)&Ws[(k + 0) * NCOLS + 4 * tx];
    float4 w1 = *(float4*)&Ws[(k + 1) * NCOLS + 4 * tx];
    float4 w2 = *(float4*)&Ws[(k + 2) * NCOLS + 4 * tx];
    float4 w3 = *(float4*)&Ws[(k + 3) * NCOLS + 4 * tx];
    #pragma unroll
    for (int r = 0; r < 8; ++r) {
      float4 a = *(const float4*)&hp[r][k];
      fma4(acc[r], a.x, w0);
      fma4(acc[r], a.y, w1);
      fma4(acc[r], a.z, w2);
      fma4(acc[r], a.w, w3);
    }
  }

  #pragma unroll
  for (int r = 0; r < 8; ++r) {
    int row = r0 + r;
    if (row < N) {
      float s = rsqrtf(fmaxf((float)ldeg[8 * ty + r], 1.0f));
      ushort4 o;
      o.x = f2bf(acc[r].x * s);
      o.y = f2bf(acc[r].y * s);
      o.z = f2bf(acc[r].z * s);
      o.w = f2bf(acc[r].w * s);
      *(ushort4*)&xg[(size_t)row * NCOLS + 4 * tx] = o;
    }
  }
}

// ---------------- bucket SpMM: presorted S + row_start, no LDS sort ---------
__global__ __launch_bounds__(512) void spmm_all_kernel(
    GArgs A, const unsigned short* __restrict__ S,
    const int* __restrict__ row_start, const unsigned short* __restrict__ x,
    float* __restrict__ out, int N, int Emax) {
  __shared__ int rs[BUCKET + 1];
  __shared__ unsigned short srcs[FCAP];

  const int t = threadIdx.x;
  const int bk = blockIdx.x;
  const int dbase = bk * BUCKET;
  const int nd = min(BUCKET, N - dbase);
  const int grp = t >> 3;          // 64 groups of 8 lanes
  const int qe = (t & 7) * 8;

  float tot[8];
  #pragma unroll
  for (int j = 0; j < 8; ++j) tot[j] = 0.f;

  for (int g = 0; g < 3; ++g) {
    const unsigned short* __restrict__ Sg = S + (size_t)g * Emax;
    const int* __restrict__ rsg = row_start + (size_t)g * (N + 1);
    const unsigned short* __restrict__ xg = x + (size_t)g * N * NCOLS;

    __syncthreads();                // protect rs/srcs from previous g
    if (t <= BUCKET) rs[t] = rsg[min(dbase + t, N)];
    __syncthreads();
    const int e0 = rs[0];
    const int ne = min(rs[BUCKET] - e0, FCAP);
    for (int i = t; i < ne; i += 512) srcs[i] = Sg[e0 + i];
    __syncthreads();

    if (grp < nd) {
      int i = rs[grp] - e0;
      const int iend = min(rs[grp + 1] - e0, ne);
      const int deg = iend - i;
      float acc[8];
      #pragma unroll
      for (int j = 0; j < 8; ++j) acc[j] = 0.f;
      for (; i + 3 < iend; i += 4) {
        int sa = srcs[i + 0];
        int sb = srcs[i + 1];
        int sc = srcs[i + 2];
        int sdd = srcs[i + 3];
        uint4 ua = *(const uint4*)&xg[(size_t)sa * NCOLS + qe];
        uint4 ub = *(const uint4*)&xg[(size_t)sb * NCOLS + qe];
        uint4 uc = *(const uint4*)&xg[(size_t)sc * NCOLS + qe];
        uint4 ud = *(const uint4*)&xg[(size_t)sdd * NCOLS + qe];
        acc[0] += bflo(ua.x) + bflo(ub.x) + bflo(uc.x) + bflo(ud.x);
        acc[1] += bfhi(ua.x) + bfhi(ub.x) + bfhi(uc.x) + bfhi(ud.x);
        acc[2] += bflo(ua.y) + bflo(ub.y) + bflo(uc.y) + bflo(ud.y);
        acc[3] += bfhi(ua.y) + bfhi(ub.y) + bfhi(uc.y) + bfhi(ud.y);
        acc[4] += bflo(ua.z) + bflo(ub.z) + bflo(uc.z) + bflo(ud.z);
        acc[5] += bfhi(ua.z) + bfhi(ub.z) + bfhi(uc.z) + bfhi(ud.z);
        acc[6] += bflo(ua.w) + bflo(ub.w) + bflo(uc.w) + bflo(ud.w);
        acc[7] += bfhi(ua.w) + bfhi(ub.w) + bfhi(uc.w) + bfhi(ud.w);
      }
      for (; i < iend; ++i) {
        int s = srcs[i];
        uint4 u = *(const uint4*)&xg[(size_t)s * NCOLS + qe];
        acc[0] += bflo(u.x); acc[1] += bfhi(u.x);
        acc[2] += bflo(u.y); acc[3] += bfhi(u.y);
        acc[4] += bflo(u.z); acc[5] += bfhi(u.z);
        acc[6] += bflo(u.w); acc[7] += bfhi(u.w);
      }
      float sc2 = rsqrtf(fmaxf((float)deg, 1.0f));
      const float* bg = A.b[g] + qe;
      #pragma unroll
      for (int j = 0; j < 8; ++j)
        tot[j] += fmaxf(fmaf(acc[j], sc2, bg[j]), 0.f) * (1.0f / 3.0f);
    }
  }

  if (grp < nd) {
    float* op = &out[(size_t)(dbase + grp) * NCOLS + qe];
    *(float4*)&op[0] = make_float4(tot[0], tot[1], tot[2], tot[3]);
    *(float4*)&op[4] = make_float4(tot[4], tot[5], tot[6], tot[7]);
  }
}

extern "C" void kernel_launch(void* const* d_in, const int* in_sizes, int n_in,
                              void* d_out, int out_size, void* d_ws, size_t ws_size,
                              hipStream_t stream) {
  const float* h = (const float*)d_in[0];
  const int N = in_sizes[0] / KDIM;   // 50000
  float* out = (float*)d_out;

  GArgs A;
  int Emax = 0;
  for (int g = 0; g < 3; ++g) {
    A.src[g] = (const int*)  d_in[1 + g * 4];
    A.dst[g] = (const int*)  d_in[2 + g * 4];
    A.W[g]   = (const float*)d_in[3 + g * 4];
    A.b[g]   = (const float*)d_in[4 + g * 4];
    A.E[g]   = in_sizes[1 + g * 4];
    if (A.E[g] > Emax) Emax = A.E[g];
  }

  // ws: x 19.2 | P2c 19.2 | P 19.3 | S 9.6 | row_start 0.6 MB | small
  char* w = (char*)d_ws;
  unsigned short* x = (unsigned short*)w;
  char*     w2 = w + (size_t)3 * N * NCOLS * sizeof(unsigned short);
  unsigned* P2c = (unsigned*)w2;
  char*     w3 = w2 + (size_t)3 * Emax * sizeof(unsigned);
  unsigned* P  = (unsigned*)w3;
  char*     w4 = w3 + (size_t)3 * NCHUNK * CWORDS * sizeof(unsigned);
  int* row_start = (int*)w4;
  char*     w5 = w4 + (size_t)3 * (N + 1) * sizeof(int);
  int* tot    = (int*)w5;                       // 3*NC
  int* off    = tot + 3 * NC;                   // 3*(NC+1)
  int* cursor = off + 3 * (NC + 1);             // 3*NC
  unsigned short* S = (unsigned short*)(cursor + 3 * NC + 2);

  hipMemsetAsync(tot, 0, 3 * NC * sizeof(int), stream);
  count_coarse_kernel<<<dim3(NPB, 3), 256, 0, stream>>>(A, tot);
  scan_off_kernel<<<1, 128, 0, stream>>>(tot, off, cursor);
  partition_coarse_kernel<<<dim3(NPB, 3), 256, 0, stream>>>(A, cursor, P2c, Emax);
  sort_fine_kernel<<<dim3(NC, 3), 512, 0, stream>>>(P2c, off, S, row_start, N, Emax);
  hist_all_kernel<<<dim3(NCHUNK, NRANGE, 3), 256, 0, stream>>>(A, P);
  gemm_all_kernel<<<dim3((N + 127) / 128, 3), 256, 0, stream>>>(A, h, P, x, N);
  spmm_all_kernel<<<NBUCK, 512, 0, stream>>>(A, S, row_start, x, out, N, Emax);
}

// Round 13
// 296.846 us; speedup vs baseline: 1.0774x; 1.0774x over previous
//
// ============================================================================
// Round 13: MFMA GEMM (bf16 h + fragment-prepacked W); rest unchanged (R12).
//
// Measured R12: 319.8 us. spmm 68.9 (bank conflicts 1.12M->6.4K after
// presort; FETCH 143 MB, Occ 40%) and gemm_all 68.9 exposed: VGPR 92,
// Occ 15.7%, 128-row tile = 64KB h-set (2x L1), latency-bound at 5 waves/CU,
// 36 TF = 23% of fp32 vector peak. ~180 us in below-cutoff CSR pipeline.
//
// Changes (gemm path only, isolate attribution):
//  - convert_h: h fp32 -> bf16 (12.8 MB) once.
//  - wfrag: prepack W_g into MFMA B-fragment layout: frag(c,kk)[lane] holds
//    W[32kk+quad*8+j][16c+n] j=0..7 as 16B -> gemm loads via coalesced uint4.
//  - gemm_mfma: 64 rows/block, 4 waves; wave = 16 rows x 64 cols =
//    16x mfma_f32_16x16x32_bf16 (A: m=lane&15,k=quad*8+j; C/D: col=lane&15,
//    row=quad*4+reg -- m89/m91-verified mapping). deg-scale+bf16 in epilogue.
//  - absmax expected ~0.004 (h,W bf16-quantized) vs threshold 0.0111.
//
// Predicted: gemm 69 -> 15-25 us (MfmaUtil >0 for the first time), +8 us for
// convert+wfrag, total 320 -> ~270-285. If gemm_mfma > 30 -> A-load
// coalescing (16 rows x 64B segments) is the suspect.
// ============================================================================
#include <hip/hip_runtime.h>

#define KDIM 128
#define NCOLS 64
// src-degree histogram (u16-packed, 2 ranges)
#define NCHUNK 64
#define NRANGE 2
#define RBINS 25088
#define RWORDS (RBINS / 2)
#define CWORDS (NRANGE * RWORDS)
// coarse buckets
#define COARSE 512
#define NC 98
#define SFCAP 17408
// fine buckets (spmm granularity)
#define BUCKET 64
#define NBUCK 782
#define FCAP 2816
// partition blocks per graph
#define NPB 85

typedef __attribute__((ext_vector_type(8))) short bf16x8;
typedef __attribute__((ext_vector_type(4))) float f32x4;

struct GArgs {
  const int*   src[3];
  const int*   dst[3];
  const float* W[3];
  const float* b[3];
  int          E[3];
};

__device__ __forceinline__ unsigned short f2bf(float f) {
  unsigned u = __float_as_uint(f);
  u += 0x7FFFu + ((u >> 16) & 1u);   // RNE
  return (unsigned short)(u >> 16);
}
__device__ __forceinline__ float bflo(unsigned u) { return __uint_as_float(u << 16); }
__device__ __forceinline__ float bfhi(unsigned u) { return __uint_as_float(u & 0xFFFF0000u); }

// ---------------- h fp32 -> bf16 (8 elems/thread) ---------------------------
__global__ __launch_bounds__(256) void convert_h_kernel(
    const float* __restrict__ h, unsigned short* __restrict__ hb, int total8) {
  int i = blockIdx.x * 256 + threadIdx.x;
  if (i >= total8) return;
  const float4* hp = (const float4*)(h + (size_t)i * 8);
  float4 f0 = hp[0];
  float4 f1 = hp[1];
  uint4 u;
  u.x = (unsigned)f2bf(f0.x) | ((unsigned)f2bf(f0.y) << 16);
  u.y = (unsigned)f2bf(f0.z) | ((unsigned)f2bf(f0.w) << 16);
  u.z = (unsigned)f2bf(f1.x) | ((unsigned)f2bf(f1.y) << 16);
  u.w = (unsigned)f2bf(f1.z) | ((unsigned)f2bf(f1.w) << 16);
  ((uint4*)hb)[i] = u;
}

// ---------------- W -> MFMA B-fragment layout -------------------------------
// Wf[((g*16 + c*4 + kk)*64 + lane)] (uint4): lane holds W[32kk+quad*8+j][16c+n]
__global__ __launch_bounds__(256) void wfrag_kernel(
    GArgs A, unsigned short* __restrict__ Wf) {
  int tid = blockIdx.x * 256 + threadIdx.x;
  if (tid >= 3 * 16 * 64) return;
  int lane = tid & 63;
  int frag = (tid >> 6) & 15;
  int g = tid >> 10;
  int c = frag >> 2, kk = frag & 3;
  int n = lane & 15, quad = lane >> 4;
  const float* W = A.W[g];
  unsigned short v[8];
  #pragma unroll
  for (int j = 0; j < 8; ++j) {
    int k = 32 * kk + quad * 8 + j;
    v[j] = f2bf(W[k * 64 + 16 * c + n]);
  }
  uint4 u;
  u.x = (unsigned)v[0] | ((unsigned)v[1] << 16);
  u.y = (unsigned)v[2] | ((unsigned)v[3] << 16);
  u.z = (unsigned)v[4] | ((unsigned)v[5] << 16);
  u.w = (unsigned)v[6] | ((unsigned)v[7] << 16);
  ((uint4*)Wf)[tid] = u;
}

// ---------------- coarse count ----------------------------------------------
__global__ __launch_bounds__(256) void count_coarse_kernel(
    GArgs A, int* __restrict__ tot) {
  __shared__ int hcnt[NC];
  const int g = blockIdx.y;
  const int E = A.E[g];
  const int per_block = (((E + NPB - 1) / NPB) + 3) & ~3;
  const int* __restrict__ dst = A.dst[g];
  const int t = threadIdx.x;
  if (t < NC) hcnt[t] = 0;
  __syncthreads();
  const int e0 = blockIdx.x * per_block;
  const int e1 = min(e0 + per_block, E);
  const int n = max(e1 - e0, 0);
  const int nv = n >> 2;
  const int4* d4 = (const int4*)&dst[e0];
  for (int v = t; v < nv; v += 256) {
    int4 d = d4[v];
    atomicAdd(&hcnt[(unsigned)d.x >> 9], 1);
    atomicAdd(&hcnt[(unsigned)d.y >> 9], 1);
    atomicAdd(&hcnt[(unsigned)d.z >> 9], 1);
    atomicAdd(&hcnt[(unsigned)d.w >> 9], 1);
  }
  for (int e = e0 + (nv << 2) + t; e < e1; e += 256)
    atomicAdd(&hcnt[(unsigned)dst[e] >> 9], 1);
  __syncthreads();
  if (t < NC && hcnt[t]) atomicAdd(&tot[g * NC + t], hcnt[t]);
}

// ---------------- exact scan ------------------------------------------------
__global__ __launch_bounds__(128) void scan_off_kernel(
    const int* __restrict__ tot, int* __restrict__ off, int* __restrict__ cursor) {
  __shared__ int sd[128];
  const int t = threadIdx.x;
  for (int g = 0; g < 3; ++g) {
    int v = (t < NC) ? tot[g * NC + t] : 0;
    sd[t] = v;
    __syncthreads();
    for (int o = 1; o < 128; o <<= 1) {
      int add = (t >= o) ? sd[t - o] : 0;
      __syncthreads();
      sd[t] += add;
      __syncthreads();
    }
    int excl = sd[t] - v;
    if (t < NC) { off[g * (NC + 1) + t] = excl; cursor[g * NC + t] = excl; }
    if (t == 0) off[g * (NC + 1) + NC] = sd[127];
    __syncthreads();
  }
}

// ---------------- coarse partition ------------------------------------------
__global__ __launch_bounds__(256) void partition_coarse_kernel(
    GArgs A, int* __restrict__ cursor, unsigned* __restrict__ P2c, int Emax) {
  __shared__ int lcnt[NC];
  __shared__ int lcur[NC];
  const int g = blockIdx.y;
  const int E = A.E[g];
  const int per_block = (((E + NPB - 1) / NPB) + 3) & ~3;
  const int* __restrict__ src = A.src[g];
  const int* __restrict__ dst = A.dst[g];
  unsigned* __restrict__ P2g = P2c + (size_t)g * Emax;
  const int t = threadIdx.x;
  if (t < NC) lcnt[t] = 0;
  __syncthreads();
  const int e0 = blockIdx.x * per_block;
  const int e1 = min(e0 + per_block, E);
  const int n = max(e1 - e0, 0);
  const int nv = n >> 2;
  const int4* d4 = (const int4*)&dst[e0];
  const int4* s4 = (const int4*)&src[e0];
  for (int v = t; v < nv; v += 256) {
    int4 d = d4[v];
    atomicAdd(&lcnt[(unsigned)d.x >> 9], 1);
    atomicAdd(&lcnt[(unsigned)d.y >> 9], 1);
    atomicAdd(&lcnt[(unsigned)d.z >> 9], 1);
    atomicAdd(&lcnt[(unsigned)d.w >> 9], 1);
  }
  for (int e = e0 + (nv << 2) + t; e < e1; e += 256)
    atomicAdd(&lcnt[(unsigned)dst[e] >> 9], 1);
  __syncthreads();
  if (t < NC) {
    int c = lcnt[t];
    lcur[t] = c ? atomicAdd(&cursor[g * NC + t], c) : 0;
  }
  __syncthreads();
  for (int v = t; v < nv; v += 256) {
    int4 d = d4[v];
    int4 s = s4[v];
    unsigned bk; int pos;
    bk = (unsigned)d.x >> 9; pos = atomicAdd(&lcur[bk], 1);
    P2g[pos] = (unsigned)s.x | (((unsigned)d.x & 511u) << 16);
    bk = (unsigned)d.y >> 9; pos = atomicAdd(&lcur[bk], 1);
    P2g[pos] = (unsigned)s.y | (((unsigned)d.y & 511u) << 16);
    bk = (unsigned)d.z >> 9; pos = atomicAdd(&lcur[bk], 1);
    P2g[pos] = (unsigned)s.z | (((unsigned)d.z & 511u) << 16);
    bk = (unsigned)d.w >> 9; pos = atomicAdd(&lcur[bk], 1);
    P2g[pos] = (unsigned)s.w | (((unsigned)d.w & 511u) << 16);
  }
  for (int e = e0 + (nv << 2) + t; e < e1; e += 256) {
    unsigned d = (unsigned)dst[e];
    unsigned bk = d >> 9;
    int pos = atomicAdd(&lcur[bk], 1);
    P2g[pos] = (unsigned)src[e] | ((d & 511u) << 16);
  }
}

// ---------------- fine sort -------------------------------------------------
__global__ __launch_bounds__(512) void sort_fine_kernel(
    const unsigned* __restrict__ P2c, const int* __restrict__ off,
    unsigned short* __restrict__ S, int* __restrict__ row_start,
    int N, int Emax) {
  __shared__ int cnt[COARSE];
  __shared__ int sd[COARSE];
  __shared__ int cur[COARSE];
  __shared__ unsigned short outl[SFCAP];
  const int c = blockIdx.x;
  const int g = blockIdx.y;
  const unsigned* __restrict__ P2g = P2c + (size_t)g * Emax;
  const int base_e = off[g * (NC + 1) + c];
  const int nloc = off[g * (NC + 1) + c + 1] - base_e;
  const int t = threadIdx.x;

  cnt[t] = 0;
  __syncthreads();
  for (int i = t; i < nloc; i += 512)
    atomicAdd(&cnt[(P2g[base_e + i] >> 16) & 511u], 1);
  __syncthreads();
  int v = cnt[t];
  sd[t] = v;
  __syncthreads();
  for (int o = 1; o < 512; o <<= 1) {
    int add = (t >= o) ? sd[t - o] : 0;
    __syncthreads();
    sd[t] += add;
    __syncthreads();
  }
  int excl = sd[t] - v;
  cur[t] = excl;
  int node = c * COARSE + t;
  if (node <= N) row_start[g * (N + 1) + node] = base_e + excl;
  __syncthreads();
  for (int i = t; i < nloc; i += 512) {
    unsigned p = P2g[base_e + i];
    int pos = atomicAdd(&cur[(p >> 16) & 511u], 1);
    if (pos < SFCAP) outl[pos] = (unsigned short)(p & 0xFFFFu);
  }
  __syncthreads();
  unsigned short* __restrict__ Sg = S + (size_t)g * Emax;
  for (int i = t; i < nloc; i += 512) Sg[base_e + i] = outl[i];
}

// ---------------- src histogram partials, u16-packed ------------------------
__global__ __launch_bounds__(256) void hist_all_kernel(
    GArgs A, unsigned* __restrict__ P) {
  __shared__ unsigned hist[RWORDS];
  const int g = blockIdx.z;
  const int E = A.E[g];
  const int per_chunk = (((E + NCHUNK - 1) / NCHUNK) + 3) & ~3;
  const int* __restrict__ keys = A.src[g];
  unsigned* __restrict__ Pg = P + (size_t)g * NCHUNK * CWORDS;

  const int chunk = blockIdx.x;
  const int base  = blockIdx.y * RBINS;
  const int t = threadIdx.x;
  for (int i = t; i < RWORDS; i += 256) hist[i] = 0;
  __syncthreads();
  const int e0 = chunk * per_chunk;
  const int e1 = min(e0 + per_chunk, E);
  const int n = max(e1 - e0, 0);
  const int nv = n >> 2;
  const int4* k4p = (const int4*)&keys[e0];
  for (int v = t; v < nv; v += 256) {
    int4 k4 = k4p[v];
    unsigned k0 = (unsigned)(k4.x - base);
    unsigned k1 = (unsigned)(k4.y - base);
    unsigned k2 = (unsigned)(k4.z - base);
    unsigned k3 = (unsigned)(k4.w - base);
    if (k0 < (unsigned)RBINS) atomicAdd(&hist[k0 >> 1], 1u << ((k0 & 1u) * 16));
    if (k1 < (unsigned)RBINS) atomicAdd(&hist[k1 >> 1], 1u << ((k1 & 1u) * 16));
    if (k2 < (unsigned)RBINS) atomicAdd(&hist[k2 >> 1], 1u << ((k2 & 1u) * 16));
    if (k3 < (unsigned)RBINS) atomicAdd(&hist[k3 >> 1], 1u << ((k3 & 1u) * 16));
  }
  for (int e = e0 + (nv << 2) + t; e < e1; e += 256) {
    unsigned k = (unsigned)(keys[e] - base);
    if (k < (unsigned)RBINS) atomicAdd(&hist[k >> 1], 1u << ((k & 1u) * 16));
  }
  __syncthreads();
  unsigned* dstp = Pg + (size_t)chunk * CWORDS + blockIdx.y * RWORDS;
  for (int i = t; i < RWORDS; i += 256) dstp[i] = hist[i];
}

// ---------------- MFMA GEMM: x(bf16) = (hb @ Wf) * rsqrt(deg) ---------------
__global__ __launch_bounds__(256) void gemm_mfma_kernel(
    GArgs A, const unsigned short* __restrict__ hb,
    const unsigned short* __restrict__ Wf, const unsigned* __restrict__ P,
    unsigned short* __restrict__ x, int N) {
  __shared__ int ldeg[64];
  const int g = blockIdx.y;
  const unsigned* __restrict__ Pg = P + (size_t)g * NCHUNK * CWORDS;
  unsigned short* __restrict__ xg = x + (size_t)g * N * NCOLS;
  const int t = threadIdx.x;
  const int row0 = blockIdx.x * 64;

  // cooperative deg: 4 threads/row x 16 chunks each
  if (t < 64) ldeg[t] = 0;
  __syncthreads();
  {
    int lrow = t >> 2;
    int part = t & 3;
    int row = min(row0 + lrow, N - 1);
    int word = row >> 1;
    int shift = (row & 1) * 16;
    int s = 0;
    #pragma unroll
    for (int c = 0; c < 16; ++c)
      s += (int)((Pg[(size_t)(part * 16 + c) * CWORDS + word] >> shift) & 0xFFFFu);
    atomicAdd(&ldeg[lrow], s);
  }

  const int lane = t & 63;
  const int w = t >> 6;            // wave id: rows row0+16w .. +15
  const int quad = lane >> 4;
  const int n = lane & 15;

  // B fragments: 16 coalesced uint4 loads (L2-hot)
  bf16x8 bf[16];
  const uint4* wfp = (const uint4*)Wf + (size_t)g * 1024 + lane;
  #pragma unroll
  for (int f = 0; f < 16; ++f) {
    union { uint4 u; bf16x8 v; } cv;
    cv.u = wfp[(size_t)f * 64];
    bf[f] = cv.v;
  }

  // A fragments: lane holds row (row0+16w+n), k = quad*8+j (+32 per frag)
  int arow = min(row0 + w * 16 + n, N - 1);
  const unsigned short* hrow = hb + (size_t)arow * KDIM + quad * 8;
  bf16x8 a0 = *(const bf16x8*)(hrow);
  bf16x8 a1 = *(const bf16x8*)(hrow + 32);
  bf16x8 a2 = *(const bf16x8*)(hrow + 64);
  bf16x8 a3 = *(const bf16x8*)(hrow + 96);

  __syncthreads();   // ldeg ready

  f32x4 acc[4];
  #pragma unroll
  for (int c = 0; c < 4; ++c) acc[c] = (f32x4)(0.f);
  #pragma unroll
  for (int c = 0; c < 4; ++c) {
    acc[c] = __builtin_amdgcn_mfma_f32_16x16x32_bf16(a0, bf[c * 4 + 0], acc[c], 0, 0, 0);
    acc[c] = __builtin_amdgcn_mfma_f32_16x16x32_bf16(a1, bf[c * 4 + 1], acc[c], 0, 0, 0);
    acc[c] = __builtin_amdgcn_mfma_f32_16x16x32_bf16(a2, bf[c * 4 + 2], acc[c], 0, 0, 0);
    acc[c] = __builtin_amdgcn_mfma_f32_16x16x32_bf16(a3, bf[c * 4 + 3], acc[c], 0, 0, 0);
  }

  // epilogue: C/D layout col = n, row = quad*4 + r
  int rbase = row0 + w * 16 + quad * 4;
  #pragma unroll
  for (int r = 0; r < 4; ++r) {
    int row = rbase + r;
    if (row < N) {
      float s = rsqrtf(fmaxf((float)ldeg[row - row0], 1.0f));
      #pragma unroll
      for (int c = 0; c < 4; ++c)
        xg[(size_t)row * NCOLS + 16 * c + n] = f2bf(acc[c][r] * s);
    }
  }
}

// ---------------- bucket SpMM (unchanged R12) -------------------------------
__global__ __launch_bounds__(512) void spmm_all_kernel(
    GArgs A, const unsigned short* __restrict__ S,
    const int* __restrict__ row_start, const unsigned short* __restrict__ x,
    float* __restrict__ out, int N, int Emax) {
  __shared__ int rs[BUCKET + 1];
  __shared__ unsigned short srcs[FCAP];

  const int t = threadIdx.x;
  const int bk = blockIdx.x;
  const int dbase = bk * BUCKET;
  const int nd = min(BUCKET, N - dbase);
  const int grp = t >> 3;
  const int qe = (t & 7) * 8;

  float tot[8];
  #pragma unroll
  for (int j = 0; j < 8; ++j) tot[j] = 0.f;

  for (int g = 0; g < 3; ++g) {
    const unsigned short* __restrict__ Sg = S + (size_t)g * Emax;
    const int* __restrict__ rsg = row_start + (size_t)g * (N + 1);
    const unsigned short* __restrict__ xg = x + (size_t)g * N * NCOLS;

    __syncthreads();
    if (t <= BUCKET) rs[t] = rsg[min(dbase + t, N)];
    __syncthreads();
    const int e0 = rs[0];
    const int ne = min(rs[BUCKET] - e0, FCAP);
    for (int i = t; i < ne; i += 512) srcs[i] = Sg[e0 + i];
    __syncthreads();

    if (grp < nd) {
      int i = rs[grp] - e0;
      const int iend = min(rs[grp + 1] - e0, ne);
      const int deg = iend - i;
      float acc[8];
      #pragma unroll
      for (int j = 0; j < 8; ++j) acc[j] = 0.f;
      for (; i + 3 < iend; i += 4) {
        int sa = srcs[i + 0];
        int sb = srcs[i + 1];
        int sc = srcs[i + 2];
        int sdd = srcs[i + 3];
        uint4 ua = *(const uint4*)&xg[(size_t)sa * NCOLS + qe];
        uint4 ub = *(const uint4*)&xg[(size_t)sb * NCOLS + qe];
        uint4 uc = *(const uint4*)&xg[(size_t)sc * NCOLS + qe];
        uint4 ud = *(const uint4*)&xg[(size_t)sdd * NCOLS + qe];
        acc[0] += bflo(ua.x) + bflo(ub.x) + bflo(uc.x) + bflo(ud.x);
        acc[1] += bfhi(ua.x) + bfhi(ub.x) + bfhi(uc.x) + bfhi(ud.x);
        acc[2] += bflo(ua.y) + bflo(ub.y) + bflo(uc.y) + bflo(ud.y);
        acc[3] += bfhi(ua.y) + bfhi(ub.y) + bfhi(uc.y) + bfhi(ud.y);
        acc[4] += bflo(ua.z) + bflo(ub.z) + bflo(uc.z) + bflo(ud.z);
        acc[5] += bfhi(ua.z) + bfhi(ub.z) + bfhi(uc.z) + bfhi(ud.z);
        acc[6] += bflo(ua.w) + bflo(ub.w) + bflo(uc.w) + bflo(ud.w);
        acc[7] += bfhi(ua.w) + bfhi(ub.w) + bfhi(uc.w) + bfhi(ud.w);
      }
      for (; i < iend; ++i) {
        int s = srcs[i];
        uint4 u = *(const uint4*)&xg[(size_t)s * NCOLS + qe];
        acc[0] += bflo(u.x); acc[1] += bfhi(u.x);
        acc[2] += bflo(u.y); acc[3] += bfhi(u.y);
        acc[4] += bflo(u.z); acc[5] += bfhi(u.z);
        acc[6] += bflo(u.w); acc[7] += bfhi(u.w);
      }
      float sc2 = rsqrtf(fmaxf((float)deg, 1.0f));
      const float* bg = A.b[g] + qe;
      #pragma unroll
      for (int j = 0; j < 8; ++j)
        tot[j] += fmaxf(fmaf(acc[j], sc2, bg[j]), 0.f) * (1.0f / 3.0f);
    }
  }

  if (grp < nd) {
    float* op = &out[(size_t)(dbase + grp) * NCOLS + qe];
    *(float4*)&op[0] = make_float4(tot[0], tot[1], tot[2], tot[3]);
    *(float4*)&op[4] = make_float4(tot[4], tot[5], tot[6], tot[7]);
  }
}

extern "C" void kernel_launch(void* const* d_in, const int* in_sizes, int n_in,
                              void* d_out, int out_size, void* d_ws, size_t ws_size,
                              hipStream_t stream) {
  const float* h = (const float*)d_in[0];
  const int N = in_sizes[0] / KDIM;   // 50000
  float* out = (float*)d_out;

  GArgs A;
  int Emax = 0;
  for (int g = 0; g < 3; ++g) {
    A.src[g] = (const int*)  d_in[1 + g * 4];
    A.dst[g] = (const int*)  d_in[2 + g * 4];
    A.W[g]   = (const float*)d_in[3 + g * 4];
    A.b[g]   = (const float*)d_in[4 + g * 4];
    A.E[g]   = in_sizes[1 + g * 4];
    if (A.E[g] > Emax) Emax = A.E[g];
  }

  // ws: x 19.2 | hb 12.8 | P2c 19.2 | P 19.3 | S 9.6 | Wf 48K | rs 0.6 MB
  char* w = (char*)d_ws;
  unsigned short* x = (unsigned short*)w;
  char* w2 = w + (size_t)3 * N * NCOLS * sizeof(unsigned short);
  unsigned short* hb = (unsigned short*)w2;
  char* w3 = w2 + (size_t)N * KDIM * sizeof(unsigned short);
  unsigned* P2c = (unsigned*)w3;
  char* w4 = w3 + (size_t)3 * Emax * sizeof(unsigned);
  unsigned* P = (unsigned*)w4;
  char* w5 = w4 + (size_t)3 * NCHUNK * CWORDS * sizeof(unsigned);
  unsigned short* S = (unsigned short*)w5;
  char* w6 = w5 + (size_t)3 * Emax * sizeof(unsigned short);
  unsigned short* Wf = (unsigned short*)w6;            // 3*16*64*8 u16 = 48 KB
  char* w7 = w6 + (size_t)3 * 16 * 64 * 8 * sizeof(unsigned short);
  int* row_start = (int*)w7;
  char* w8 = w7 + (size_t)3 * (N + 1) * sizeof(int);
  int* tot    = (int*)w8;
  int* off    = tot + 3 * NC;
  int* cursor = off + 3 * (NC + 1);

  hipMemsetAsync(tot, 0, 3 * NC * sizeof(int), stream);
  {
    int total8 = N * KDIM / 8;
    convert_h_kernel<<<(total8 + 255) / 256, 256, 0, stream>>>(h, hb, total8);
  }
  wfrag_kernel<<<12, 256, 0, stream>>>(A, Wf);
  count_coarse_kernel<<<dim3(NPB, 3), 256, 0, stream>>>(A, tot);
  scan_off_kernel<<<1, 128, 0, stream>>>(tot, off, cursor);
  partition_coarse_kernel<<<dim3(NPB, 3), 256, 0, stream>>>(A, cursor, P2c, Emax);
  sort_fine_kernel<<<dim3(NC, 3), 512, 0, stream>>>(P2c, off, S, row_start, N, Emax);
  hist_all_kernel<<<dim3(NCHUNK, NRANGE, 3), 256, 0, stream>>>(A, P);
  gemm_mfma_kernel<<<dim3((N + 63) / 64, 3), 256, 0, stream>>>(A, hb, Wf, P, x, N);
  spmm_all_kernel<<<NBUCK, 512, 0, stream>>>(A, S, row_start, x, out, N, Emax);
}